// Round 11
// baseline (611.895 us; speedup 1.0000x reference)
//
#include <hip/hip_runtime.h>
#include <math.h>

#define KD     768     // embedding dim (elements = bytes in fp8)
#define MT     64      // M tile (queries) per block (4-wave blocks)
#define NT     128     // N tile (bank rows)
#define KB     128     // K bytes per mfma_scale (K=128)
#define CHK    16384   // bytes per staged K-chunk (128 rows x 128 B)
#define TILEB  98304   // bytes per bf8 N-tile (NT * KD)
#define NKC    6       // K chunks per tile (768/128)
#define NSPLIT 32      // bank splits per M tile
#define BIGF   3.0e38f

typedef __attribute__((ext_vector_type(4))) int   i32x4;
typedef __attribute__((ext_vector_type(8))) int   i32x8;
typedef __attribute__((ext_vector_type(4))) float f32x4;

// ---- software RNE float -> OCP e4m3fn (data ~N(0,1); saturation irrelevant)
__device__ __forceinline__ unsigned f2e4m3(float x) {
    unsigned u = __float_as_uint(x);
    unsigned s = (u >> 24) & 0x80u;
    float ax = __uint_as_float(u & 0x7fffffffu);
    if (ax < 0.015625f) {                       // subnormal region: step 2^-9
        int n = (int)rintf(ax * 512.0f);        // RNE, n in [0,8]
        if (n >= 8) return s | 0x08u;
        return s | (unsigned)n;
    }
    if (ax >= 464.0f) return s | 0x7Eu;         // saturate to 448
    unsigned m = __float_as_uint(ax);
    unsigned low = m & 0xFFFFFu;
    unsigned r = m >> 20;
    r += (low > 0x80000u) || (low == 0x80000u && (r & 1u));
    int ef = (int)(r >> 3) - 120;               // -127 + 7 (carry-safe)
    return s | ((unsigned)ef << 3) | (r & 7u);
}

__device__ __forceinline__ void ins3(float* t, float v) {
    float lo0 = fminf(t[0], v);
    float hi0 = fmaxf(t[0], v);
    float lo1 = fminf(t[1], hi0);
    float hi1 = fmaxf(t[1], hi0);
    float lo2 = fminf(t[2], hi1);
    t[0] = lo0; t[1] = lo1; t[2] = lo2;
}
__device__ __forceinline__ void async16(unsigned char* lds, const unsigned char* g) {
    __builtin_amdgcn_global_load_lds(
        (const __attribute__((address_space(1))) unsigned int*)g,
        (__attribute__((address_space(3))) unsigned int*)lds, 16, 0, 0);
}

// ---- emb [B][768][1024] -> qf8 [B*1024][768] e4m3 + q2 partials (atomicAdd) ----
// grid = B * 16 hw-tiles * 12 e-groups (64 e each) = 1536 blocks (6/CU).
__global__ void q_prep_k(const float* __restrict__ emb, unsigned char* __restrict__ qf8,
                         float* __restrict__ q2) {
    __shared__ float s[64][65];
    int bx  = blockIdx.x;
    int b   = bx / 192;
    int rem = bx % 192;
    int hw0 = (rem & 15) * 64;
    int eg  = rem >> 4;                           // 0..11
    int e0  = eg * 64;
    const float* src = emb + (size_t)b * KD * 1024;
    unsigned int* q4 = (unsigned int*)qf8;
    #pragma unroll
    for (int i = 0; i < 16; ++i) {
        int idx = threadIdx.x + i * 256;          // 0..4095
        int ee = idx >> 6, hh = idx & 63;
        s[ee][hh] = src[(size_t)(e0 + ee) * 1024 + hw0 + hh];
    }
    __syncthreads();
    #pragma unroll
    for (int i = 0; i < 4; ++i) {
        int slot = threadIdx.x + i * 256;         // 0..1023 : (qq, e4)
        int qq = slot >> 4, e4 = slot & 15;
        float v0 = s[e4 * 4 + 0][qq], v1 = s[e4 * 4 + 1][qq];
        float v2 = s[e4 * 4 + 2][qq], v3 = s[e4 * 4 + 3][qq];
        unsigned p = f2e4m3(v0) | (f2e4m3(v1) << 8)
                   | (f2e4m3(v2) << 16) | (f2e4m3(v3) << 24);
        q4[((size_t)b * 1024 + hw0 + qq) * (KD / 4) + e0 / 4 + e4] = p;
        float part = 0.f;
        part = fmaf(v0, v0, part); part = fmaf(v1, v1, part);
        part = fmaf(v2, v2, part); part = fmaf(v3, v3, part);
        #pragma unroll
        for (int off = 1; off < 16; off <<= 1) part += __shfl_xor(part, off, 64);
        if ((threadIdx.x & 15) == 0) atomicAdd(&q2[b * 1024 + hw0 + qq], part);
    }
}

// ---- bank -> bf8 e4m3 in GROUP-MAJOR tile layout + exact fp32 b2 norms ----
// bf8 byte layout: [nt][kc][G=0..7][m=0..127][16B], holding bank row
// (nt*128+m), K bytes kc*128 + G*16 + [0,16). This makes knn's LDS staging a
// pure linear memcpy AND the frag reads conflict-free: a quarter-wave (16
// lanes, l15=0..15) reads m=16ni+l15 -> 16x16B CONTIGUOUS = all 32 banks
// exactly once (old row-major layout: 128B row stride -> banks from offset
// only -> 8 slots for 16 lanes = 2-way alias = 1.5e7 conflict cy).
// One block per 128-row tile; fp32 slab staged in LDS per kc so global
// reads AND writes stay coalesced. b2 accumulated in registers across kc.
__global__ void bank_prep_k(const float* __restrict__ bank, unsigned char* __restrict__ bf8,
                            float* __restrict__ b2, int N, int Npad) {
    __shared__ float s[128][129];                 // kc slab: 128 rows x 128 floats
    const int tid = threadIdx.x;
    const int nt  = blockIdx.x;
    const int r0  = nt * 128;
    unsigned int* out = (unsigned int*)bf8;
    const int myrow  = tid >> 1;                  // b2: 2 threads per row
    const int myhalf = tid & 1;
    float racc = 0.f;
    for (int kc = 0; kc < NKC; ++kc) {
        __syncthreads();                          // prior kc's readers done
        #pragma unroll
        for (int i = 0; i < 64; ++i) {            // 16384 floats, coalesced
            int idx = tid + i * 256;
            int row = idx >> 7, c = idx & 127;
            int rg = r0 + row;
            float v = (rg < N) ? bank[(size_t)rg * KD + kc * KB + c] : 0.f;
            s[row][c] = v;
        }
        __syncthreads();
        // b2 partial for this kc (row fixed per thread across kc)
        #pragma unroll
        for (int j = 0; j < 64; ++j) {
            float v = s[myrow][myhalf * 64 + j];
            racc = fmaf(v, v, racc);
        }
        // convert + write 16 KB in tile layout, coalesced dwords
        #pragma unroll
        for (int i = 0; i < 16; ++i) {
            int d = tid + i * 256;                // 0..4095 dwords
            int G = d >> 9, m = (d >> 2) & 127, b4 = d & 3;
            float f0 = s[m][G * 16 + b4 * 4 + 0];
            float f1 = s[m][G * 16 + b4 * 4 + 1];
            float f2 = s[m][G * 16 + b4 * 4 + 2];
            float f3 = s[m][G * 16 + b4 * 4 + 3];
            unsigned p = f2e4m3(f0) | (f2e4m3(f1) << 8)
                       | (f2e4m3(f2) << 16) | (f2e4m3(f3) << 24);
            out[(size_t)nt * (TILEB / 4) + kc * 4096 + d] = p;
        }
    }
    float pair = racc + __shfl_xor(racc, 1, 64);
    if (myhalf == 0) {
        int rg = r0 + myrow;
        if (rg < Npad) b2[rg] = (rg < N) ? pair : BIGF;
    }
}

// ---- stage one 32 KB window (kc pair): PURE LINEAR COPY (bf8 pre-laid-out)
__device__ __forceinline__ void stage_w(unsigned char* buf, const unsigned char* gT,
                                        int off, int tid) {
    #pragma unroll
    for (int h = 0; h < 2; ++h)
        #pragma unroll
        for (int i = 0; i < 4; ++i) {
            int s = (tid + i * 256) * 16;
            async16(buf + h * CHK + s, gT + off + h * CHK + s);
        }
}

__device__ __forceinline__ i32x8 frag_read(const unsigned char* st, int base) {
    i32x4 lo = *(const i32x4*)&st[base];          // K bytes quad*32 + [0,16)
    i32x4 hi = *(const i32x4*)&st[base + 2048];   // K bytes quad*32 + [16,32)
    return __builtin_shufflevector(lo, hi, 0, 1, 2, 3, 4, 5, 6, 7);
}

// ---- main: fp8 MFMA distance GEMM + fused top-3 ----
// R7 structure/order restored (best: 210us; R10's stage hoist was -12us,
// reverted). Change vs R7: group-major B layout (see bank_prep_k) ->
//  * stage_w = linear coalesced memcpy (no address math, no src swizzle)
//  * frag reads conflict-free: quarter-wave reads 256B contiguous
// Cycle model (R10 diagnosis): wall == LDS service time (2275 cy/slot =
// 1536 read + 512 DMA-write + 256 conflict). This removes the 256 and
// should cut per-read cost (12+4 -> ~8 cy) -> slot ~1800 cy.
// Register model (R4/R5/R6 data): alloc/wave = 2 x max(arch, AGPR) of 512
// -> arch <= 128 for 2 waves/SIMD -> af=96 caps mi=2 (structural).
// LDS: 2 x 32 KB dbuf + b2s = 66.6 KB -> 2 blocks/CU.
__global__ __launch_bounds__(256, 2)
void knn_mfma_k(const unsigned char* __restrict__ qf8, const unsigned char* __restrict__ bf8,
                const float* __restrict__ b2g, float* __restrict__ cand,
                int ntiles, int Q) {
    __shared__ unsigned char bst[2][2 * CHK];     // 2 x 32 KB window dbuf
    __shared__ float b2s[5 * NT];                 // numnt <= 5 b2 tiles

    const int tid  = threadIdx.x;
    const int lane = tid & 63;
    const int quad = lane >> 4;
    const int l15  = lane & 15;
    const int wid  = tid >> 6;                    // 0..3
    const int wm   = wid & 1;                     // M half (32 rows)
    const int wn   = wid >> 1;                    // N half (64 cols)

    const int bx   = blockIdx.x;
    const int xcd  = bx & 7;
    const int rr_  = bx >> 9;                     // temporal round 0..7
    const int jj   = (bx >> 3) & 63;
    const int mt   = xcd * 16 + (jj & 15);        // 0..127, 16 mts per XCD
    const int sp   = (jj >> 4) + 4 * rr_;         // 0..31
    const int Mbase = mt * MT;

    const int numnt = (ntiles - sp + NSPLIT - 1) / NSPLIT; // 4 or 5

    // prologue: b2 for this block's N tiles -> LDS (keeps main loop VMEM-free)
    for (int idx = tid; idx < numnt * NT; idx += 256) {
        int slot = idx >> 7, col = idx & 127;
        b2s[idx] = b2g[(size_t)(sp + slot * NSPLIT) * NT + col];
    }

    // prologue: A (this wave's 32 rows, full K=768) -> registers.
    // 16x16x128 A layout: row = l15, K bytes = quad*32 + [0,32).
    const unsigned char* gA = qf8 + ((size_t)Mbase + 32 * wm + l15) * KD + quad * 32;
    i32x8 af[NKC][2];
    #pragma unroll
    for (int kc = 0; kc < NKC; ++kc)
        #pragma unroll
        for (int mi = 0; mi < 2; ++mi) {
            const i32x4* p = (const i32x4*)(gA + (size_t)mi * 16 * KD + kc * KB);
            i32x4 lo = p[0];
            i32x4 hi = p[1];
            af[kc][mi] = __builtin_shufflevector(lo, hi, 0, 1, 2, 3, 4, 5, 6, 7);
        }

    float top3[24];
    #pragma unroll
    for (int i = 0; i < 24; ++i) top3[i] = BIGF;
    f32x4 acc[2][4];
    #pragma unroll
    for (int a = 0; a < 2; ++a)
        #pragma unroll
        for (int b = 0; b < 4; ++b) acc[a][b] = (f32x4){0.f, 0.f, 0.f, 0.f};

    // frag base in group-major chunk: G=2q at quad*4096 (+2048 for o=1),
    // m = 64*wn + 16*ni + l15 at m*16
    int bb[4];
    #pragma unroll
    for (int ni = 0; ni < 4; ++ni)
        bb[ni] = quad * 4096 + (64 * wn + 16 * ni + l15) * 16 + 256 * 0,
        bb[ni] = quad * 4096 + 1024 * wn + 256 * ni + 16 * l15;

    __syncthreads();                              // drains all prologue mem ops

    // prefetch window 0 (kc 0,1) of first tile
    const unsigned char* gT0 = bf8 + (size_t)sp * TILEB;
    stage_w(bst[0], gT0, 0, tid);

    int pp = 0;
    for (int i = 0; i < numnt; ++i) {
        const unsigned char* gTc = bf8 + (size_t)(sp + i * NSPLIT) * TILEB;
        const bool lastt = (i == numnt - 1);
        const unsigned char* gTn = lastt ? gTc
                                 : bf8 + (size_t)(sp + (i + 1) * NSPLIT) * TILEB;
        #pragma unroll
        for (int w = 0; w < 3; ++w) {             // window = kc {2w, 2w+1}
            asm volatile("s_waitcnt vmcnt(0)" ::: "memory");
            __builtin_amdgcn_s_barrier();         // window resident, prior reads done
            const unsigned char* st = bst[pp];
            // kcA frags first: ds_read latency starts immediately
            i32x8 ba[4];
            #pragma unroll
            for (int ni = 0; ni < 4; ++ni) ba[ni] = frag_read(st, bb[ni]);
            // issue next window's DMAs (overlaps frag latency) - R7 placement
            if (!(lastt && w == 2)) {
                if (w < 2) stage_w(bst[pp ^ 1], gTc, (2 * w + 2) * CHK, tid);
                else       stage_w(bst[pp ^ 1], gTn, 0, tid);
            }
            // kcB frags: latency hidden under kcA's MFMAs (counted lgkmcnt)
            i32x8 bbf[4];
            #pragma unroll
            for (int ni = 0; ni < 4; ++ni)
                bbf[ni] = frag_read(st + CHK, bb[ni]);
            #pragma unroll
            for (int ni = 0; ni < 4; ++ni)
                #pragma unroll
                for (int mi = 0; mi < 2; ++mi)
                    acc[mi][ni] = __builtin_amdgcn_mfma_scale_f32_16x16x128_f8f6f4(
                        af[2 * w][mi], ba[ni], acc[mi][ni], 0, 0,
                        0, 127, 0, 127);          // identity E8M0 scales
            #pragma unroll
            for (int ni = 0; ni < 4; ++ni)
                #pragma unroll
                for (int mi = 0; mi < 2; ++mi)
                    acc[mi][ni] = __builtin_amdgcn_mfma_scale_f32_16x16x128_f8f6f4(
                        af[2 * w + 1][mi], bbf[ni], acc[mi][ni], 0, 0,
                        0, 127, 0, 127);
            pp ^= 1;
        }
        // epilogue: s = b2 - 2*dot (q2 added in scores_k; per-row const
        // preserves order). Overlaps the in-flight next-window DMAs.
        const float* b2p = &b2s[i * NT + 64 * wn];
        #pragma unroll
        for (int ni = 0; ni < 4; ++ni) {
            float b2v = b2p[16 * ni + l15];
            #pragma unroll
            for (int mi = 0; mi < 2; ++mi)
                #pragma unroll
                for (int r = 0; r < 4; ++r) {
                    float s = fmaf(-2.0f, acc[mi][ni][r], b2v);
                    ins3(&top3[(mi * 4 + r) * 3], s);
                }
        }
        #pragma unroll
        for (int a = 0; a < 2; ++a)
            #pragma unroll
            for (int b = 0; b < 4; ++b) acc[a][b] = (f32x4){0.f, 0.f, 0.f, 0.f};
    }

    // merge the 16 column-partials per query row via shfl_xor butterfly.
    // cand layout [q][partial] so scores_k reads coalesce.
    #pragma unroll
    for (int mi = 0; mi < 2; ++mi)
        #pragma unroll
        for (int r = 0; r < 4; ++r) {
            float a0 = top3[(mi * 4 + r) * 3 + 0];
            float a1 = top3[(mi * 4 + r) * 3 + 1];
            float a2 = top3[(mi * 4 + r) * 3 + 2];
            #pragma unroll
            for (int off = 1; off < 16; off <<= 1) {
                float b0 = __shfl_xor(a0, off, 64);
                float b1 = __shfl_xor(a1, off, 64);
                float b2x = __shfl_xor(a2, off, 64);
                float t[3] = {a0, a1, a2};
                ins3(t, b0); ins3(t, b1); ins3(t, b2x);
                a0 = t[0]; a1 = t[1]; a2 = t[2];
            }
            if (l15 == 0) {
                int row = Mbase + 32 * wm + 16 * mi + 4 * quad + r;
                float* o = cand + ((size_t)row * 64 + (sp * 2 + wn)) * 3;
                o[0] = a0; o[1] = a1; o[2] = a2;
            }
        }
}

// ---- merge 64 split-partials: one WAVE per query, lane = partial ----
// cand is [q][64 partials][3]: a wave reads 768 B contiguous (coalesced).
__global__ void scores_k(const float* __restrict__ cand, const float* __restrict__ q2g,
                         float* __restrict__ scores, int Q) {
    int gid  = blockIdx.x * 256 + threadIdx.x;
    int q    = gid >> 6;
    int lane = gid & 63;
    if (q >= Q) return;
    const float* c = cand + ((size_t)q * 64 + lane) * 3;
    float a0 = c[0], a1 = c[1], a2 = c[2];
    #pragma unroll
    for (int off = 1; off < 64; off <<= 1) {
        float b0 = __shfl_xor(a0, off, 64);
        float b1 = __shfl_xor(a1, off, 64);
        float b2x = __shfl_xor(a2, off, 64);
        float t[3] = {a0, a1, a2};
        ins3(t, b0); ins3(t, b1); ins3(t, b2x);
        a0 = t[0]; a1 = t[1]; a2 = t[2];
    }
    if (lane == 0) {
        float q2 = q2g[q];
        float s = (sqrtf(fmaxf(q2 + a0, 1e-12f)) +
                   sqrtf(fmaxf(q2 + a1, 1e-12f)) +
                   sqrtf(fmaxf(q2 + a2, 1e-12f))) * (1.f / 3.f);
        scores[q] = s;
    }
}

// ---- bilinear x16 upsample, half-pixel, edge clamp ----
__global__ void upsample_k(const float* __restrict__ scores, float* __restrict__ out, int total) {
    int idx = blockIdx.x * blockDim.x + threadIdx.x;
    if (idx >= total) return;
    int x = idx & 511;
    int y = (idx >> 9) & 511;
    int b = idx >> 18;
    float sx = (x + 0.5f) * (1.f / 16.f) - 0.5f;
    float sy = (y + 0.5f) * (1.f / 16.f) - 0.5f;
    int x0 = (int)floorf(sx);
    int y0 = (int)floorf(sy);
    float wx = sx - (float)x0;
    float wy = sy - (float)y0;
    int x0c = min(max(x0, 0), 31), x1c = min(max(x0 + 1, 0), 31);
    int y0c = min(max(y0, 0), 31), y1c = min(max(y0 + 1, 0), 31);
    const float* sb = scores + (size_t)b * 1024;
    float v00 = sb[y0c * 32 + x0c], v01 = sb[y0c * 32 + x1c];
    float v10 = sb[y1c * 32 + x0c], v11 = sb[y1c * 32 + x1c];
    float v0 = v00 + wx * (v01 - v00);
    float v1 = v10 + wx * (v11 - v10);
    out[idx] = v0 + wy * (v1 - v0);
}

extern "C" void kernel_launch(void* const* d_in, const int* in_sizes, int n_in,
                              void* d_out, int out_size, void* d_ws, size_t ws_size,
                              hipStream_t stream) {
    const float* emb  = (const float*)d_in[0];
    const float* bank = (const float*)d_in[1];
    const int Q      = in_sizes[0] / KD;             // 8192
    const int B      = Q / 1024;                     // 8
    const int Nbank  = in_sizes[1] / KD;             // 20000
    const int ntiles = (Nbank + NT - 1) / NT;        // 157
    const int Npad   = ntiles * NT;                  // 20096
    const int Mtiles = Q / MT;                       // 128

    // workspace layout
    unsigned char* qf8 = (unsigned char*)d_ws;                         // Q*KD bytes
    unsigned char* bf8 = qf8 + (size_t)Q * KD;                         // Npad*KD bytes
    float* fbase  = (float*)(bf8 + (size_t)Npad * KD);
    float* q2     = fbase;                                             // Q
    float* b2     = q2 + Q;                                            // Npad
    float* cand   = b2 + Npad;                                         // Q*64*3 (transposed)
    float* scores = cand + (size_t)Q * 64 * 3;                         // Q
    float* out    = (float*)d_out;

    hipMemsetAsync(q2, 0, Q * sizeof(float), stream);  // q2 accumulated via atomicAdd
    hipLaunchKernelGGL(q_prep_k, dim3(B * 192), dim3(256), 0, stream, emb, qf8, q2);
    hipLaunchKernelGGL(bank_prep_k, dim3(ntiles), dim3(256), 0, stream,
                       bank, bf8, b2, Nbank, Npad);
    hipLaunchKernelGGL(knn_mfma_k, dim3(Mtiles * NSPLIT), dim3(256), 0, stream,
                       qf8, bf8, b2, cand, ntiles, Q);
    hipLaunchKernelGGL(scores_k, dim3((Q * 64 + 255) / 256), dim3(256), 0, stream,
                       cand, q2, scores, Q);
    hipLaunchKernelGGL(upsample_k, dim3((out_size + 255) / 256), dim3(256), 0, stream,
                       scores, out, out_size);
}